// Round 3
// baseline (105359.216 us; speedup 1.0000x reference)
//
#include <hip/hip_runtime.h>
#include <hip/hip_bf16.h>
#include <math.h>

typedef unsigned short u16;
typedef unsigned int   u32;
typedef __attribute__((ext_vector_type(8))) short short8;
typedef __attribute__((ext_vector_type(4))) float float4v;

#define BB 64
#define SS 512

// bf16 helpers (RNE)
__device__ __forceinline__ u16 f2b(float f) {
    u32 x = __float_as_uint(f);
    u32 r = (x + 0x7fffu + ((x >> 16) & 1u)) >> 16;
    return (u16)r;
}
__device__ __forceinline__ float b2f(u32 lo16) {           // low 16 bits
    return __uint_as_float(lo16 << 16);
}
__device__ __forceinline__ float b2fh(u32 v) {             // high 16 bits in place
    return __uint_as_float(v & 0xffff0000u);
}

// ---------------------------------------------------------------------------
// pe[s][2j] = sin(s*10000^(-2j/512)), pe[s][2j+1] = cos(...)
// ---------------------------------------------------------------------------
__global__ __launch_bounds__(256) void pe_kernel(float* __restrict__ pe) {
    int s = blockIdx.x, j = threadIdx.x;
    float ang = (float)s * powf(10000.0f, -(2.0f * (float)j) / 512.0f);
    pe[s * 512 + 2 * j]     = sinf(ang);
    pe[s * 512 + 2 * j + 1] = cosf(ang);
}

// ---------------------------------------------------------------------------
// fp32 [R][C] -> bf16 [C][R]  (weight prep: Wcomb, Wq, Wk, Wv)
// ---------------------------------------------------------------------------
__global__ __launch_bounds__(256) void transp_w(const float* __restrict__ in,
                                                u16* __restrict__ out, int R, int C) {
    __shared__ float t[64][65];
    int r0 = blockIdx.x * 64, c0 = blockIdx.y * 64;
    int tid = threadIdx.x;
    int lr = tid >> 4, lc4 = (tid & 15) * 4;
#pragma unroll
    for (int i = 0; i < 4; i++) {
        int r = lr + i * 16;
        float4 v = *(const float4*)(in + (long)(r0 + r) * C + c0 + lc4);
        t[r][lc4] = v.x; t[r][lc4 + 1] = v.y; t[r][lc4 + 2] = v.z; t[r][lc4 + 3] = v.w;
    }
    __syncthreads();
#pragma unroll
    for (int i = 0; i < 4; i++) {
        int c = lr + i * 16;
        u32 lo = (u32)f2b(t[lc4][c])     | ((u32)f2b(t[lc4 + 1][c]) << 16);
        u32 hi = (u32)f2b(t[lc4 + 2][c]) | ((u32)f2b(t[lc4 + 3][c]) << 16);
        uint2 pk; pk.x = lo; pk.y = hi;
        *(uint2*)(out + (long)(c0 + c) * R + r0 + lc4) = pk;
    }
}

// ---------------------------------------------------------------------------
// fp32 -> bf16 elementwise (Wi)
// ---------------------------------------------------------------------------
__global__ __launch_bounds__(256) void cvt_bf16(const float* __restrict__ in,
                                                u16* __restrict__ out, long n) {
    long i = (long)blockIdx.x * 256 + threadIdx.x;
    if (i < n) out[i] = f2b(in[i]);
}

// ---------------------------------------------------------------------------
// bf16 [nb][R][C] -> out[b][c][r] with element strides (Vt and zp permute)
// ---------------------------------------------------------------------------
__global__ __launch_bounds__(256) void transp_b(const u16* __restrict__ in,
                                                u16* __restrict__ out,
                                                int R, int C, long sbin, long sb, long sc) {
    __shared__ u32 t[64][65];
    int bz = blockIdx.z;
    in += (long)bz * sbin;
    int r0 = blockIdx.x * 64, c0 = blockIdx.y * 64;
    int tid = threadIdx.x;
    int lr = tid >> 4, lc4 = (tid & 15) * 4;
#pragma unroll
    for (int i = 0; i < 4; i++) {
        int r = lr + i * 16;
        uint2 v = *(const uint2*)(in + (long)(r0 + r) * C + c0 + lc4);
        t[r][lc4] = v.x & 0xffffu; t[r][lc4 + 1] = v.x >> 16;
        t[r][lc4 + 2] = v.y & 0xffffu; t[r][lc4 + 3] = v.y >> 16;
    }
    __syncthreads();
#pragma unroll
    for (int i = 0; i < 4; i++) {
        int c = lr + i * 16;
        uint2 pk;
        pk.x = t[lc4][c] | (t[lc4 + 1][c] << 16);
        pk.y = t[lc4 + 2][c] | (t[lc4 + 3][c] << 16);
        *(uint2*)(out + (long)bz * sb + (long)(c0 + c) * sc + r0 + lc4) = pk;
    }
}

// ---------------------------------------------------------------------------
// Embedding + continuous projection -> bf16 xcat chunk [4096][1024]
// ---------------------------------------------------------------------------
__global__ __launch_bounds__(256) void embed_kernel(
    const int* __restrict__ cate, const float* __restrict__ cont,
    const float* __restrict__ emb, const float* __restrict__ Wc,
    const float* __restrict__ bc, u16* __restrict__ xc, int gbase)
{
    long bs = (long)gbase + blockIdx.x;
    long r  = blockIdx.x;
    __shared__ float cf[6];
    if (threadIdx.x < 6) cf[threadIdx.x] = cont[bs * 6 + threadIdx.x];
    __syncthreads();
    for (int h = threadIdx.x; h < 1024; h += 256) {
        float v;
        if (h < 512) {
            int c = h >> 7, e = h & 127;
            int idx = cate[bs * 4 + c];
            v = emb[((long)c * 1000 + idx) * 128 + e];
        } else {
            int hh = h - 512;
            v = bc[hh];
#pragma unroll
            for (int f = 0; f < 6; f++) v += cf[f] * Wc[f * 512 + hh];
        }
        xc[r * 1024 + h] = f2b(v);
    }
}

// ---------------------------------------------------------------------------
// bf16 MFMA NT GEMM: C[M,N] = alpha * A[M,K] @ B[N,K]^T (+bias) (+pe)
// 128x128 tile, BK=32, 256 threads (4 waves, each 64x64 via 4x4 MFMA tiles).
// All dims multiples of 128 (M,N) and 32 (K). Batched via grid.z.
// ---------------------------------------------------------------------------
__global__ __launch_bounds__(256) void gemm_nt(
    const u16* __restrict__ A, const u16* __restrict__ B, void* __restrict__ Cv,
    int K, int lda, int ldb, int ldc,
    long sA, long sB, long sC,
    const float* __restrict__ bias, const float* __restrict__ pe,
    float alpha, int outBf16)
{
    __shared__ u16 As[128][40];
    __shared__ u16 Bs[128][40];

    A += (long)blockIdx.z * sA;
    B += (long)blockIdx.z * sB;
    int m0 = blockIdx.y * 128, n0 = blockIdx.x * 128;
    int tid = threadIdx.x;
    int lane = tid & 63, wid = tid >> 6;
    int wm = (wid >> 1) * 64, wn = (wid & 1) * 64;
    int mrow = lane & 15, q8 = (lane >> 4) * 8;

    float4v acc[4][4];
#pragma unroll
    for (int i = 0; i < 4; i++)
#pragma unroll
        for (int j = 0; j < 4; j++) { float4v z = {0.f, 0.f, 0.f, 0.f}; acc[i][j] = z; }

    for (int k0 = 0; k0 < K; k0 += 32) {
        {
            int r = tid >> 2, sg = tid & 3;
            *(short8*)&As[r][sg * 8] = *(const short8*)(A + (long)(m0 + r) * lda + k0 + sg * 8);
            *(short8*)&Bs[r][sg * 8] = *(const short8*)(B + (long)(n0 + r) * ldb + k0 + sg * 8);
            r = (tid + 256) >> 2;
            *(short8*)&As[r][sg * 8] = *(const short8*)(A + (long)(m0 + r) * lda + k0 + sg * 8);
            *(short8*)&Bs[r][sg * 8] = *(const short8*)(B + (long)(n0 + r) * ldb + k0 + sg * 8);
        }
        __syncthreads();
        short8 af[4], bfr[4];
#pragma unroll
        for (int t = 0; t < 4; t++) {
            af[t]  = *(const short8*)&As[wm + t * 16 + mrow][q8];
            bfr[t] = *(const short8*)&Bs[wn + t * 16 + mrow][q8];
        }
#pragma unroll
        for (int i = 0; i < 4; i++)
#pragma unroll
            for (int j = 0; j < 4; j++)
                acc[i][j] = __builtin_amdgcn_mfma_f32_16x16x32_bf16(af[i], bfr[j], acc[i][j], 0, 0, 0);
        __syncthreads();
    }

    int col = lane & 15, quad = lane >> 4;
    u16*  Cb = (u16*)Cv  + (outBf16 ? (long)blockIdx.z * sC : 0);
    float* Cf = (float*)Cv + (outBf16 ? 0 : (long)blockIdx.z * sC);
#pragma unroll
    for (int i = 0; i < 4; i++)
#pragma unroll
        for (int j = 0; j < 4; j++) {
#pragma unroll
            for (int rr = 0; rr < 4; rr++) {
                int gm = m0 + wm + i * 16 + quad * 4 + rr;
                int gn = n0 + wn + j * 16 + col;
                float v = acc[i][j][rr] * alpha;
                if (bias) v += bias[gn];
                if (pe)   v += pe[(long)(gm & 511) * 512 + gn];
                if (outBf16) Cb[(long)gm * ldc + gn] = f2b(v);
                else         Cf[(long)gm * ldc + gn] = v;
            }
        }
}

// ---------------------------------------------------------------------------
// Softmax over QUERY axis of S[8][512 q][512 k] fp32 -> P bf16 same layout
// ---------------------------------------------------------------------------
__global__ __launch_bounds__(64) void softmax_q(const float* __restrict__ S,
                                                u16* __restrict__ P) {
    int b = blockIdx.x;
    int k = blockIdx.y * 64 + threadIdx.x;
    const float* p = S + (long)b * 262144 + k;
    u16* o = P + (long)b * 262144 + k;
    float m = -1e30f;
    for (int q = 0; q < 512; q++) m = fmaxf(m, p[(long)q * 512]);
    float sum = 0.f;
    for (int q = 0; q < 512; q++) sum += expf(p[(long)q * 512] - m);
    float inv = 1.f / sum;
    for (int q = 0; q < 512; q++) o[(long)q * 512] = f2b(expf(p[(long)q * 512] - m) * inv);
}

// ---------------------------------------------------------------------------
// GRU segment: 64 blocks (1 per batch), 256 threads (2 units each), nsteps.
// h kept fp32 in LDS (double-buffered); Wh fp32 streamed from L2.
// gi: [nsteps*64][1536] fp32 (includes bi). Writes seq_out bf16 rows (s0+sl)*64+b.
// ---------------------------------------------------------------------------
__global__ __launch_bounds__(256) void gru_seg(
    const float* __restrict__ gi, const float* __restrict__ Wh_l,
    const float* __restrict__ bh_l, u16* __restrict__ seq_out,
    float* __restrict__ hbuf, int s0, int nsteps)
{
    __shared__ float hs[2][512];
    int b = blockIdx.x, tid = threadIdx.x;
    int u0 = tid * 2;

    if (s0 == 0) { hs[0][u0] = 0.f; hs[0][u0 + 1] = 0.f; }
    else { hs[0][u0] = hbuf[b * 512 + u0]; hs[0][u0 + 1] = hbuf[b * 512 + u0 + 1]; }
    __syncthreads();

    float bhr0 = bh_l[u0],        bhr1 = bh_l[u0 + 1];
    float bhz0 = bh_l[512 + u0],  bhz1 = bh_l[512 + u0 + 1];
    float bhn0 = bh_l[1024 + u0], bhn1 = bh_l[1024 + u0 + 1];

    const float4* wr0 = (const float4*)(Wh_l + (long)u0 * 512);
    const float4* wr1 = (const float4*)(Wh_l + (long)(u0 + 1) * 512);
    const float4* wz0 = (const float4*)(Wh_l + (long)(512 + u0) * 512);
    const float4* wz1 = (const float4*)(Wh_l + (long)(513 + u0) * 512);
    const float4* wn0 = (const float4*)(Wh_l + (long)(1024 + u0) * 512);
    const float4* wn1 = (const float4*)(Wh_l + (long)(1025 + u0) * 512);

    for (int sl = 0; sl < nsteps; sl++) {
        int cur = sl & 1, nxt = cur ^ 1;
        const float4* h4 = (const float4*)hs[cur];
        float ar0 = 0.f, ar1 = 0.f, az0 = 0.f, az1 = 0.f, an0 = 0.f, an1 = 0.f;
#pragma unroll 4
        for (int k = 0; k < 128; k++) {
            float4 h = h4[k];
            float4 a;
            a = wr0[k]; ar0 += a.x * h.x + a.y * h.y + a.z * h.z + a.w * h.w;
            a = wr1[k]; ar1 += a.x * h.x + a.y * h.y + a.z * h.z + a.w * h.w;
            a = wz0[k]; az0 += a.x * h.x + a.y * h.y + a.z * h.z + a.w * h.w;
            a = wz1[k]; az1 += a.x * h.x + a.y * h.y + a.z * h.z + a.w * h.w;
            a = wn0[k]; an0 += a.x * h.x + a.y * h.y + a.z * h.z + a.w * h.w;
            a = wn1[k]; an1 += a.x * h.x + a.y * h.y + a.z * h.z + a.w * h.w;
        }
        const float* g = gi + ((long)sl * 64 + b) * 1536;
        float r0 = 1.f / (1.f + expf(-(g[u0]       + ar0 + bhr0)));
        float r1 = 1.f / (1.f + expf(-(g[u0 + 1]   + ar1 + bhr1)));
        float z0 = 1.f / (1.f + expf(-(g[512 + u0] + az0 + bhz0)));
        float z1 = 1.f / (1.f + expf(-(g[513 + u0] + az1 + bhz1)));
        float n0 = tanhf(g[1024 + u0] + r0 * (an0 + bhn0));
        float n1 = tanhf(g[1025 + u0] + r1 * (an1 + bhn1));
        float hp0 = hs[cur][u0], hp1 = hs[cur][u0 + 1];
        float h0n = (1.f - z0) * n0 + z0 * hp0;
        float h1n = (1.f - z1) * n1 + z1 * hp1;
        hs[nxt][u0] = h0n; hs[nxt][u0 + 1] = h1n;
        u32 pk = (u32)f2b(h0n) | ((u32)f2b(h1n) << 16);
        *(u32*)(seq_out + ((long)(s0 + sl) * 64 + b) * 512 + u0) = pk;
        __syncthreads();
    }
    int fin = nsteps & 1;
    hbuf[b * 512 + u0]     = hs[fin][u0];
    hbuf[b * 512 + u0 + 1] = hs[fin][u0 + 1];
}

// ---------------------------------------------------------------------------
// out[b][s] = sigmoid( dot(h2[s*64+b, :], Wf) + bf )  — one wave per row
// ---------------------------------------------------------------------------
__global__ __launch_bounds__(256) void final_kernel(
    const u16* __restrict__ h2, const float* __restrict__ Wf,
    const float* __restrict__ bfin, float* __restrict__ out)
{
    int w = blockIdx.x * 4 + (threadIdx.x >> 6);
    int lane = threadIdx.x & 63;
    const u16* row = h2 + (long)w * 512;
    uint4 hv = *(const uint4*)(row + lane * 8);
    float4 w0 = *(const float4*)(Wf + lane * 8);
    float4 w1 = *(const float4*)(Wf + lane * 8 + 4);
    float sum = b2f(hv.x & 0xffffu) * w0.x + b2fh(hv.x) * w0.y
              + b2f(hv.y & 0xffffu) * w0.z + b2fh(hv.y) * w0.w
              + b2f(hv.z & 0xffffu) * w1.x + b2fh(hv.z) * w1.y
              + b2f(hv.w & 0xffffu) * w1.z + b2fh(hv.w) * w1.w;
#pragma unroll
    for (int off = 32; off > 0; off >>= 1) sum += __shfl_down(sum, off, 64);
    if (lane == 0) {
        int s = w >> 6, b = w & 63;
        out[(long)b * 512 + s] = 1.f / (1.f + expf(-(sum + bfin[0])));
    }
}

// ---------------------------------------------------------------------------
// Launcher — workspace footprint ~166.4 MB
// ---------------------------------------------------------------------------
extern "C" void kernel_launch(void* const* d_in, const int* in_sizes, int n_in,
                              void* d_out, int out_size, void* d_ws, size_t ws_size,
                              hipStream_t stream) {
    const int*   cate  = (const int*)  d_in[0];
    const float* cont  = (const float*)d_in[1];
    const float* emb   = (const float*)d_in[4];
    const float* Wc    = (const float*)d_in[5];
    const float* bc    = (const float*)d_in[6];
    const float* Wcomb = (const float*)d_in[7];
    const float* bcomb = (const float*)d_in[8];
    const float* Wq    = (const float*)d_in[9];
    const float* Wk    = (const float*)d_in[10];
    const float* Wv    = (const float*)d_in[11];
    const float* Wi    = (const float*)d_in[12];
    const float* Wh    = (const float*)d_in[13];
    const float* bi    = (const float*)d_in[14];
    const float* bh    = (const float*)d_in[15];
    const float* Wf    = (const float*)d_in[16];
    const float* bfin  = (const float*)d_in[17];
    float* out = (float*)d_out;
    char* ws = (char*)d_ws;

    // ---- workspace layout (bytes) ----
    u16*   zp    = (u16*)(ws + 0);            // [512*64][512] bf16 ; later h2bf (alias)
    u16*   h2bf  = (u16*)(ws + 0);
    u16*   h1bf  = (u16*)(ws + 33554432);     // [512*64][512] bf16
    float* gi    = (float*)(ws + 67108864);   // [128*64][1536] fp32 (50.3MB), aliases xbf
    u16*   xbf   = (u16*)(ws + 67108864);     // [32768][512] bf16 (33.5MB)
    u16*   Qg    = (u16*)(ws + 117440512);    // [8][512][512]
    u16*   Kg    = (u16*)(ws + 121634816);
    u16*   Vg    = (u16*)(ws + 125829120);
    u16*   Vt    = (u16*)(ws + 130023424);
    float* Sg    = (float*)(ws + 134217728);  // [8][512][512] fp32
    u16*   Pg    = (u16*)(ws + 142606336);
    u16*   zT    = (u16*)(ws + 146800640);
    u16*   xc    = (u16*)(ws + 150994944);    // [4096][1024] bf16 chunk
    u16*   WcombT= (u16*)(ws + 159383552);    // [512][1024]
    u16*   WqT   = (u16*)(ws + 160432128);    // [512][512]
    u16*   WkT   = (u16*)(ws + 160956416);
    u16*   WvT   = (u16*)(ws + 161480704);
    u16*   WiB   = (u16*)(ws + 162004992);    // [2][1536][512]
    float* pe    = (float*)(ws + 165150720);  // [512][512] fp32
    float* hbuf  = (float*)(ws + 166199296);  // [64][512] fp32

    // ---- weight prep ----
    transp_w<<<dim3(16, 8), 256, 0, stream>>>(Wcomb, WcombT, 1024, 512);
    transp_w<<<dim3(8, 8),  256, 0, stream>>>(Wq, WqT, 512, 512);
    transp_w<<<dim3(8, 8),  256, 0, stream>>>(Wk, WkT, 512, 512);
    transp_w<<<dim3(8, 8),  256, 0, stream>>>(Wv, WvT, 512, 512);
    cvt_bf16<<<6144, 256, 0, stream>>>(Wi, WiB, 2L * 1536 * 512);
    pe_kernel<<<512, 256, 0, stream>>>(pe);

    // ---- phase 1: x = bf16( xcat @ Wcomb + bcomb + pe ), 8 chunks of 4096 rows
    for (int g = 0; g < 8; g++) {
        embed_kernel<<<4096, 256, 0, stream>>>(cate, cont, emb, Wc, bc, xc, g * 4096);
        gemm_nt<<<dim3(4, 32, 1), 256, 0, stream>>>(
            xc, WcombT, xbf + (long)g * 4096 * 512, 1024, 1024, 1024, 512,
            0, 0, 0, bcomb, pe, 1.f, 1);
    }

    // ---- phase 2: attention in 8 batch-groups of 8
    for (int g = 0; g < 8; g++) {
        const u16* xg = xbf + (long)g * 8 * 512 * 512;
        gemm_nt<<<dim3(4, 32, 1), 256, 0, stream>>>(xg, WqT, Qg, 512, 512, 512, 512,
                                                    0, 0, 0, nullptr, nullptr, 1.f, 1);
        gemm_nt<<<dim3(4, 32, 1), 256, 0, stream>>>(xg, WkT, Kg, 512, 512, 512, 512,
                                                    0, 0, 0, nullptr, nullptr, 1.f, 1);
        gemm_nt<<<dim3(4, 32, 1), 256, 0, stream>>>(xg, WvT, Vg, 512, 512, 512, 512,
                                                    0, 0, 0, nullptr, nullptr, 1.f, 1);
        transp_b<<<dim3(8, 8, 8), 256, 0, stream>>>(Vg, Vt, 512, 512, 262144, 262144, 512);
        // S[b] = Q[b] @ K[b]^T * (1/sqrt(512))  -> fp32
        gemm_nt<<<dim3(4, 4, 8), 256, 0, stream>>>(Qg, Kg, Sg, 512, 512, 512, 512,
                                                   262144, 262144, 262144, nullptr, nullptr,
                                                   0.04419417382415922f, 0);
        softmax_q<<<dim3(8, 8), 64, 0, stream>>>(Sg, Pg);
        // zT[b] = Vt[b] @ P[b]^T  (= z^T)
        gemm_nt<<<dim3(4, 4, 8), 256, 0, stream>>>(Vt, Pg, zT, 512, 512, 512, 512,
                                                   262144, 262144, 262144, nullptr, nullptr,
                                                   1.f, 1);
        // zp[q][bglobal][d] = zT[b][d][q]
        transp_b<<<dim3(8, 8, 8), 256, 0, stream>>>(zT, zp + (long)g * 8 * 512,
                                                    512, 512, 262144, 512, 32768);
    }

    // ---- phase 3: 2 GRU layers, gi in 4 segments of 128 steps each
    for (int l = 0; l < 2; l++) {
        const u16* Aseq = (l == 0) ? zp : h1bf;
        u16* seqOut = (l == 0) ? h1bf : h2bf;
        const u16* WiL = WiB + (long)l * 1536 * 512;
        const float* WhL = Wh + (long)l * 1536 * 512;
        const float* biL = bi + (long)l * 1536;
        const float* bhL = bh + (long)l * 1536;
        for (int seg = 0; seg < 4; seg++) {
            gemm_nt<<<dim3(12, 64, 1), 256, 0, stream>>>(
                Aseq + (long)seg * 128 * 64 * 512, WiL, gi, 512, 512, 512, 1536,
                0, 0, 0, biL, nullptr, 1.f, 0);
            gru_seg<<<64, 256, 0, stream>>>(gi, WhL, bhL, seqOut, hbuf, seg * 128, 128);
        }
    }

    // ---- final
    final_kernel<<<8192, 256, 0, stream>>>(h2bf, Wf, bfin, out);
}

// Round 5
// 54459.167 us; speedup vs baseline: 1.9346x; 1.9346x over previous
//
#include <hip/hip_runtime.h>
#include <hip/hip_bf16.h>
#include <math.h>

typedef unsigned short u16;
typedef unsigned int   u32;
typedef __attribute__((ext_vector_type(8))) short short8;
typedef __attribute__((ext_vector_type(4))) float float4v;

#define BB 64
#define SS 512

// bf16 helpers (RNE)
__device__ __forceinline__ u16 f2b(float f) {
    u32 x = __float_as_uint(f);
    u32 r = (x + 0x7fffu + ((x >> 16) & 1u)) >> 16;
    return (u16)r;
}
__device__ __forceinline__ float b2f(u32 lo16) { return __uint_as_float(lo16 << 16); }
__device__ __forceinline__ float b2fh(u32 v)   { return __uint_as_float(v & 0xffff0000u); }

// ---------------------------------------------------------------------------
__global__ __launch_bounds__(256) void zero_kernel(float* __restrict__ p, int n) {
    int i = blockIdx.x * 256 + threadIdx.x;
    if (i < n) p[i] = 0.f;
}

// ---------------------------------------------------------------------------
__global__ __launch_bounds__(256) void pe_kernel(float* __restrict__ pe) {
    int s = blockIdx.x, j = threadIdx.x;
    float ang = (float)s * powf(10000.0f, -(2.0f * (float)j) / 512.0f);
    pe[s * 512 + 2 * j]     = sinf(ang);
    pe[s * 512 + 2 * j + 1] = cosf(ang);
}

// ---------------------------------------------------------------------------
// fp32 [R][C] -> bf16 [C][R]
// ---------------------------------------------------------------------------
__global__ __launch_bounds__(256) void transp_w(const float* __restrict__ in,
                                                u16* __restrict__ out, int R, int C) {
    __shared__ float t[64][65];
    int r0 = blockIdx.x * 64, c0 = blockIdx.y * 64;
    int tid = threadIdx.x;
    int lr = tid >> 4, lc4 = (tid & 15) * 4;
#pragma unroll
    for (int i = 0; i < 4; i++) {
        int r = lr + i * 16;
        float4 v = *(const float4*)(in + (long)(r0 + r) * C + c0 + lc4);
        t[r][lc4] = v.x; t[r][lc4 + 1] = v.y; t[r][lc4 + 2] = v.z; t[r][lc4 + 3] = v.w;
    }
    __syncthreads();
#pragma unroll
    for (int i = 0; i < 4; i++) {
        int c = lr + i * 16;
        u32 lo = (u32)f2b(t[lc4][c])     | ((u32)f2b(t[lc4 + 1][c]) << 16);
        u32 hi = (u32)f2b(t[lc4 + 2][c]) | ((u32)f2b(t[lc4 + 3][c]) << 16);
        uint2 pk; pk.x = lo; pk.y = hi;
        *(uint2*)(out + (long)(c0 + c) * R + r0 + lc4) = pk;
    }
}

// ---------------------------------------------------------------------------
__global__ __launch_bounds__(256) void cvt_bf16(const float* __restrict__ in,
                                                u16* __restrict__ out, long n) {
    long i = (long)blockIdx.x * 256 + threadIdx.x;
    if (i < n) out[i] = f2b(in[i]);
}

// ---------------------------------------------------------------------------
// bf16 [nb][R][C] -> out[b][c][r] with element strides
// ---------------------------------------------------------------------------
__global__ __launch_bounds__(256) void transp_b(const u16* __restrict__ in,
                                                u16* __restrict__ out,
                                                int R, int C, long sbin, long sb, long sc) {
    __shared__ u32 t[64][65];
    int bz = blockIdx.z;
    in += (long)bz * sbin;
    int r0 = blockIdx.x * 64, c0 = blockIdx.y * 64;
    int tid = threadIdx.x;
    int lr = tid >> 4, lc4 = (tid & 15) * 4;
#pragma unroll
    for (int i = 0; i < 4; i++) {
        int r = lr + i * 16;
        uint2 v = *(const uint2*)(in + (long)(r0 + r) * C + c0 + lc4);
        t[r][lc4] = v.x & 0xffffu; t[r][lc4 + 1] = v.x >> 16;
        t[r][lc4 + 2] = v.y & 0xffffu; t[r][lc4 + 3] = v.y >> 16;
    }
    __syncthreads();
#pragma unroll
    for (int i = 0; i < 4; i++) {
        int c = lr + i * 16;
        uint2 pk;
        pk.x = t[lc4][c] | (t[lc4 + 1][c] << 16);
        pk.y = t[lc4 + 2][c] | (t[lc4 + 3][c] << 16);
        *(uint2*)(out + (long)bz * sb + (long)(c0 + c) * sc + r0 + lc4) = pk;
    }
}

// ---------------------------------------------------------------------------
__global__ __launch_bounds__(256) void embed_kernel(
    const int* __restrict__ cate, const float* __restrict__ cont,
    const float* __restrict__ emb, const float* __restrict__ Wc,
    const float* __restrict__ bc, u16* __restrict__ xc, int gbase)
{
    long bs = (long)gbase + blockIdx.x;
    long r  = blockIdx.x;
    __shared__ float cf[6];
    if (threadIdx.x < 6) cf[threadIdx.x] = cont[bs * 6 + threadIdx.x];
    __syncthreads();
    for (int h = threadIdx.x; h < 1024; h += 256) {
        float v;
        if (h < 512) {
            int c = h >> 7, e = h & 127;
            int idx = cate[bs * 4 + c];
            v = emb[((long)c * 1000 + idx) * 128 + e];
        } else {
            int hh = h - 512;
            v = bc[hh];
#pragma unroll
            for (int f = 0; f < 6; f++) v += cf[f] * Wc[f * 512 + hh];
        }
        xc[r * 1024 + h] = f2b(v);
    }
}

// ---------------------------------------------------------------------------
// bf16 MFMA NT GEMM (validated in R3, absmax 0.0)
// ---------------------------------------------------------------------------
__global__ __launch_bounds__(256) void gemm_nt(
    const u16* __restrict__ A, const u16* __restrict__ B, void* __restrict__ Cv,
    int K, int lda, int ldb, int ldc,
    long sA, long sB, long sC,
    const float* __restrict__ bias, const float* __restrict__ pe,
    float alpha, int outBf16)
{
    __shared__ u16 As[128][40];
    __shared__ u16 Bs[128][40];

    A += (long)blockIdx.z * sA;
    B += (long)blockIdx.z * sB;
    int m0 = blockIdx.y * 128, n0 = blockIdx.x * 128;
    int tid = threadIdx.x;
    int lane = tid & 63, wid = tid >> 6;
    int wm = (wid >> 1) * 64, wn = (wid & 1) * 64;
    int mrow = lane & 15, q8 = (lane >> 4) * 8;

    float4v acc[4][4];
#pragma unroll
    for (int i = 0; i < 4; i++)
#pragma unroll
        for (int j = 0; j < 4; j++) { float4v z = {0.f, 0.f, 0.f, 0.f}; acc[i][j] = z; }

    for (int k0 = 0; k0 < K; k0 += 32) {
        {
            int r = tid >> 2, sg = tid & 3;
            *(short8*)&As[r][sg * 8] = *(const short8*)(A + (long)(m0 + r) * lda + k0 + sg * 8);
            *(short8*)&Bs[r][sg * 8] = *(const short8*)(B + (long)(n0 + r) * ldb + k0 + sg * 8);
            r = (tid + 256) >> 2;
            *(short8*)&As[r][sg * 8] = *(const short8*)(A + (long)(m0 + r) * lda + k0 + sg * 8);
            *(short8*)&Bs[r][sg * 8] = *(const short8*)(B + (long)(n0 + r) * ldb + k0 + sg * 8);
        }
        __syncthreads();
        short8 af[4], bfr[4];
#pragma unroll
        for (int t = 0; t < 4; t++) {
            af[t]  = *(const short8*)&As[wm + t * 16 + mrow][q8];
            bfr[t] = *(const short8*)&Bs[wn + t * 16 + mrow][q8];
        }
#pragma unroll
        for (int i = 0; i < 4; i++)
#pragma unroll
            for (int j = 0; j < 4; j++)
                acc[i][j] = __builtin_amdgcn_mfma_f32_16x16x32_bf16(af[i], bfr[j], acc[i][j], 0, 0, 0);
        __syncthreads();
    }

    int col = lane & 15, quad = lane >> 4;
    u16*  Cb = (u16*)Cv  + (outBf16 ? (long)blockIdx.z * sC : 0);
    float* Cf = (float*)Cv + (outBf16 ? 0 : (long)blockIdx.z * sC);
#pragma unroll
    for (int i = 0; i < 4; i++)
#pragma unroll
        for (int j = 0; j < 4; j++) {
#pragma unroll
            for (int rr = 0; rr < 4; rr++) {
                int gm = m0 + wm + i * 16 + quad * 4 + rr;
                int gn = n0 + wn + j * 16 + col;
                float v = acc[i][j][rr] * alpha;
                if (bias) v += bias[gn];
                if (pe)   v += pe[(long)(gm & 511) * 512 + gn];
                if (outBf16) Cb[(long)gm * ldc + gn] = f2b(v);
                else         Cf[(long)gm * ldc + gn] = v;
            }
        }
}

// ---------------------------------------------------------------------------
// Softmax over QUERY axis fp32 -> bf16
// ---------------------------------------------------------------------------
__global__ __launch_bounds__(64) void softmax_q(const float* __restrict__ S,
                                                u16* __restrict__ P) {
    int b = blockIdx.x;
    int k = blockIdx.y * 64 + threadIdx.x;
    const float* p = S + (long)b * 262144 + k;
    u16* o = P + (long)b * 262144 + k;
    float m = -1e30f;
    for (int q = 0; q < 512; q++) m = fmaxf(m, p[(long)q * 512]);
    float sum = 0.f;
    for (int q = 0; q < 512; q++) sum += expf(p[(long)q * 512] - m);
    float inv = 1.f / sum;
    for (int q = 0; q < 512; q++) o[(long)q * 512] = f2b(expf(p[(long)q * 512] - m) * inv);
}

// ---------------------------------------------------------------------------
// Cooperative persistent GRU, 128-step segment. fp32 Wh in LDS (exact R3
// numerics), fp32 h recurrence.
// Grid 256 = 8 batch-groups(8 batches) x 32 unit-slices(16 units).
// LDS: Wh slice 48x512 fp32 (stride 529, col-skew col+col/32) ~99KB
//      h 8x512 fp32 (stride 640, col-skew col+(col/32)*8)     ~20KB
//      psum [16q][8b][16u][3g]                                ~24KB
// ---------------------------------------------------------------------------
__global__ __launch_bounds__(256, 1) void gru_coop(
    const float* __restrict__ gi,     // [128][64][1536] fp32 (includes bi)
    const float* __restrict__ Wh_l,   // [1536][512] fp32
    const float* __restrict__ bh_l,   // [1536]
    u16* __restrict__ seq_out,        // [512*64][512] bf16
    float* __restrict__ hg,           // [2][64][512] fp32
    u32* __restrict__ cnt,
    int s0, int sync_base)
{
    __shared__ float whl[48 * 529];
    __shared__ float hl[8 * 640];
    __shared__ float psum[16][8][16][3];

    int blk = blockIdx.x;
    int grp = blk >> 5;          // 0..7  batch group (8 batches)
    int ubk = blk & 31;          // 0..31 unit slice (16 units)
    int ub  = ubk * 16;
    int tid = threadIdx.x;
    int ut  = tid & 15;
    int q   = tid >> 4;          // 0..15 (32-col slice)

    // --- Wh slice -> LDS fp32, once per segment ---
    for (int i = tid; i < 48 * 128; i += 256) {
        int r  = i >> 7;                 // 0..47 = gate*16 + unit
        int c4 = (i & 127) << 2;
        int g  = r >> 4, u = r & 15;
        float4 f = *(const float4*)(Wh_l + ((long)(g * 512 + ub + u)) * 512 + c4);
        int p = r * 529 + c4 + (c4 >> 5);
        whl[p] = f.x; whl[p + 1] = f.y; whl[p + 2] = f.z; whl[p + 3] = f.w;
    }

    // gate-phase constants (threads 0..127: btg = tid>>4 in 0..7, unit ut)
    float bhv0 = 0.f, bhv1 = 0.f, bhv2 = 0.f;
    int btg = tid >> 4;
    if (tid < 128) {
        bhv0 = bh_l[ub + ut];
        bhv1 = bh_l[512 + ub + ut];
        bhv2 = bh_l[1024 + ub + ut];
    }

    // --- init h ---
    if (s0 == 0) {
        for (int i = tid; i < 8 * 640; i += 256) hl[i] = 0.f;
    } else {
        const float* src = hg + (long)(s0 & 1) * 32768 + grp * 8 * 512;
        for (int i = tid; i < 1024; i += 256) {
            int b = i >> 7, c4 = (i & 127) << 2;
            float4 f = *(const float4*)(src + b * 512 + c4);
            *(float4*)&hl[b * 640 + c4 + ((c4 >> 5) << 3)] = f;
        }
    }
    __syncthreads();

    const int qoff_h = q * 40;
    const int w0off = (ut) * 529 + q * 33;
    const int w1off = (16 + ut) * 529 + q * 33;
    const int w2off = (32 + ut) * 529 + q * 33;

    for (int sl = 0; sl < 128; sl++) {
        int gstep = s0 + sl;

        float acc0[8], acc1[8], acc2[8];
#pragma unroll
        for (int b = 0; b < 8; b++) { acc0[b] = 0.f; acc1[b] = 0.f; acc2[b] = 0.f; }

#pragma unroll
        for (int c8 = 0; c8 < 8; c8++) {
            int hc = qoff_h + c8 * 4;
            float4 hb[8];
#pragma unroll
            for (int b = 0; b < 8; b++) hb[b] = *(const float4*)&hl[b * 640 + hc];
            int wc = c8 * 4;
            float a0 = whl[w0off + wc], a1 = whl[w0off + wc + 1],
                  a2 = whl[w0off + wc + 2], a3 = whl[w0off + wc + 3];
            float b0 = whl[w1off + wc], b1 = whl[w1off + wc + 1],
                  b2 = whl[w1off + wc + 2], b3 = whl[w1off + wc + 3];
            float c0 = whl[w2off + wc], c1 = whl[w2off + wc + 1],
                  c2 = whl[w2off + wc + 2], c3 = whl[w2off + wc + 3];
#pragma unroll
            for (int b = 0; b < 8; b++) {
                float4 h = hb[b];
                acc0[b] += a0 * h.x + a1 * h.y + a2 * h.z + a3 * h.w;
                acc1[b] += b0 * h.x + b1 * h.y + b2 * h.z + b3 * h.w;
                acc2[b] += c0 * h.x + c1 * h.y + c2 * h.z + c3 * h.w;
            }
        }
#pragma unroll
        for (int b = 0; b < 8; b++) {
            psum[q][b][ut][0] = acc0[b];
            psum[q][b][ut][1] = acc1[b];
            psum[q][b][ut][2] = acc2[b];
        }
        __syncthreads();

        // --- gate math on 128 threads ---
        if (tid < 128) {
            float sr = 0.f, sz = 0.f, sn = 0.f;
#pragma unroll
            for (int qq = 0; qq < 16; qq++) {
                sr += psum[qq][btg][ut][0];
                sz += psum[qq][btg][ut][1];
                sn += psum[qq][btg][ut][2];
            }
            const float* g = gi + ((long)sl * 64 + grp * 8 + btg) * 1536;
            int col = ub + ut;
            float ir = g[col], iz = g[512 + col], inn = g[1024 + col];
            float r  = 1.f / (1.f + expf(-(ir + sr + bhv0)));
            float zg = 1.f / (1.f + expf(-(iz + sz + bhv1)));
            float n  = tanhf(inn + r * (sn + bhv2));
            float hprev = hl[btg * 640 + col + ((col >> 5) << 3)];
            float hn = (1.f - zg) * n + zg * hprev;
            hg[(long)((gstep + 1) & 1) * 32768 + (grp * 8 + btg) * 512 + col] = hn;
            seq_out[((long)gstep * 64 + grp * 8 + btg) * 512 + col] = f2b(hn);
        }

        // --- device-scope barrier ---
        __threadfence();
        __syncthreads();
        if (tid == 0) {
            __hip_atomic_fetch_add(cnt, 1u, __ATOMIC_RELEASE, __HIP_MEMORY_SCOPE_AGENT);
            u32 target = 256u * (u32)(sync_base + sl + 1);
            while (__hip_atomic_load(cnt, __ATOMIC_ACQUIRE, __HIP_MEMORY_SCOPE_AGENT) < target) {
                __builtin_amdgcn_s_sleep(2);
            }
        }
        __syncthreads();
        __threadfence();

        // --- reload h (our 8 batches) ---
        const float* src = hg + (long)((gstep + 1) & 1) * 32768 + grp * 8 * 512;
        for (int i = tid; i < 1024; i += 256) {
            int b = i >> 7, c4 = (i & 127) << 2;
            float4 f = *(const float4*)(src + b * 512 + c4);
            *(float4*)&hl[b * 640 + c4 + ((c4 >> 5) << 3)] = f;
        }
        __syncthreads();
    }
}

// ---------------------------------------------------------------------------
__global__ __launch_bounds__(256) void final_kernel(
    const u16* __restrict__ h2, const float* __restrict__ Wf,
    const float* __restrict__ bfin, float* __restrict__ out)
{
    int w = blockIdx.x * 4 + (threadIdx.x >> 6);
    int lane = threadIdx.x & 63;
    const u16* row = h2 + (long)w * 512;
    uint4 hv = *(const uint4*)(row + lane * 8);
    float4 w0 = *(const float4*)(Wf + lane * 8);
    float4 w1 = *(const float4*)(Wf + lane * 8 + 4);
    float sum = b2f(hv.x & 0xffffu) * w0.x + b2fh(hv.x) * w0.y
              + b2f(hv.y & 0xffffu) * w0.z + b2fh(hv.y) * w0.w
              + b2f(hv.z & 0xffffu) * w1.x + b2fh(hv.z) * w1.y
              + b2f(hv.w & 0xffffu) * w1.z + b2fh(hv.w) * w1.w;
#pragma unroll
    for (int off = 32; off > 0; off >>= 1) sum += __shfl_down(sum, off, 64);
    if (lane == 0) {
        int s = w >> 6, b = w & 63;
        out[(long)b * 512 + s] = 1.f / (1.f + expf(-(sum + bfin[0])));
    }
}

// ---------------------------------------------------------------------------
// Launcher — workspace ~166.5 MB
// ---------------------------------------------------------------------------
extern "C" void kernel_launch(void* const* d_in, const int* in_sizes, int n_in,
                              void* d_out, int out_size, void* d_ws, size_t ws_size,
                              hipStream_t stream) {
    const int*   cate  = (const int*)  d_in[0];
    const float* cont  = (const float*)d_in[1];
    const float* emb   = (const float*)d_in[4];
    const float* Wc    = (const float*)d_in[5];
    const float* bc    = (const float*)d_in[6];
    const float* Wcomb = (const float*)d_in[7];
    const float* bcomb = (const float*)d_in[8];
    const float* Wq    = (const float*)d_in[9];
    const float* Wk    = (const float*)d_in[10];
    const float* Wv    = (const float*)d_in[11];
    const float* Wi    = (const float*)d_in[12];
    const float* Wh    = (const float*)d_in[13];
    const float* bi    = (const float*)d_in[14];
    const float* bh    = (const float*)d_in[15];
    const float* Wf    = (const float*)d_in[16];
    const float* bfin  = (const float*)d_in[17];
    float* out = (float*)d_out;
    char* ws = (char*)d_ws;

    u16*   zp    = (u16*)(ws + 0);
    u16*   h2bf  = (u16*)(ws + 0);
    u16*   h1bf  = (u16*)(ws + 33554432);
    float* gi    = (float*)(ws + 67108864);   // 50.3 MB, aliases xbf
    u16*   xbf   = (u16*)(ws + 67108864);
    u16*   Qg    = (u16*)(ws + 117440512);
    u16*   Kg    = (u16*)(ws + 121634816);
    u16*   Vg    = (u16*)(ws + 125829120);
    u16*   Vt    = (u16*)(ws + 130023424);
    float* Sg    = (float*)(ws + 134217728);
    u16*   Pg    = (u16*)(ws + 142606336);
    u16*   zT    = (u16*)(ws + 146800640);
    u16*   xc    = (u16*)(ws + 150994944);
    u16*   WcombT= (u16*)(ws + 159383552);
    u16*   WqT   = (u16*)(ws + 160432128);
    u16*   WkT   = (u16*)(ws + 160956416);
    u16*   WvT   = (u16*)(ws + 161480704);
    u16*   WiB   = (u16*)(ws + 162004992);
    float* pe    = (float*)(ws + 165150720);
    float* hg    = (float*)(ws + 166199296);  // [2][64][512] fp32
    u32*   cnt   = (u32*)  (ws + 166461440);

    zero_kernel<<<1, 256, 0, stream>>>((float*)cnt, 1);
    transp_w<<<dim3(16, 8), 256, 0, stream>>>(Wcomb, WcombT, 1024, 512);
    transp_w<<<dim3(8, 8),  256, 0, stream>>>(Wq, WqT, 512, 512);
    transp_w<<<dim3(8, 8),  256, 0, stream>>>(Wk, WkT, 512, 512);
    transp_w<<<dim3(8, 8),  256, 0, stream>>>(Wv, WvT, 512, 512);
    cvt_bf16<<<6144, 256, 0, stream>>>(Wi, WiB, 2L * 1536 * 512);
    pe_kernel<<<512, 256, 0, stream>>>(pe);

    // phase 1
    for (int g = 0; g < 8; g++) {
        embed_kernel<<<4096, 256, 0, stream>>>(cate, cont, emb, Wc, bc, xc, g * 4096);
        gemm_nt<<<dim3(4, 32, 1), 256, 0, stream>>>(
            xc, WcombT, xbf + (long)g * 4096 * 512, 1024, 1024, 1024, 512,
            0, 0, 0, bcomb, pe, 1.f, 1);
    }

    // phase 2
    for (int g = 0; g < 8; g++) {
        const u16* xg = xbf + (long)g * 8 * 512 * 512;
        gemm_nt<<<dim3(4, 32, 1), 256, 0, stream>>>(xg, WqT, Qg, 512, 512, 512, 512,
                                                    0, 0, 0, nullptr, nullptr, 1.f, 1);
        gemm_nt<<<dim3(4, 32, 1), 256, 0, stream>>>(xg, WkT, Kg, 512, 512, 512, 512,
                                                    0, 0, 0, nullptr, nullptr, 1.f, 1);
        gemm_nt<<<dim3(4, 32, 1), 256, 0, stream>>>(xg, WvT, Vg, 512, 512, 512, 512,
                                                    0, 0, 0, nullptr, nullptr, 1.f, 1);
        transp_b<<<dim3(8, 8, 8), 256, 0, stream>>>(Vg, Vt, 512, 512, 262144, 262144, 512);
        gemm_nt<<<dim3(4, 4, 8), 256, 0, stream>>>(Qg, Kg, Sg, 512, 512, 512, 512,
                                                   262144, 262144, 262144, nullptr, nullptr,
                                                   0.04419417382415922f, 0);
        softmax_q<<<dim3(8, 8), 64, 0, stream>>>(Sg, Pg);
        gemm_nt<<<dim3(4, 4, 8), 256, 0, stream>>>(Vt, Pg, zT, 512, 512, 512, 512,
                                                   262144, 262144, 262144, nullptr, nullptr,
                                                   1.f, 1);
        transp_b<<<dim3(8, 8, 8), 256, 0, stream>>>(zT, zp + (long)g * 8 * 512,
                                                    512, 512, 262144, 512, 32768);
    }

    // phase 3: GRU
    for (int l = 0; l < 2; l++) {
        const u16* Aseq = (l == 0) ? zp : h1bf;
        u16* seqOut = (l == 0) ? h1bf : h2bf;
        const u16* WiL = WiB + (long)l * 1536 * 512;
        const float* WhL = Wh + (long)l * 1536 * 512;
        const float* biL = bi + (long)l * 1536;
        const float* bhL = bh + (long)l * 1536;
        for (int seg = 0; seg < 4; seg++) {
            gemm_nt<<<dim3(12, 64, 1), 256, 0, stream>>>(
                Aseq + (long)seg * 128 * 64 * 512, WiL, gi, 512, 512, 512, 1536,
                0, 0, 0, biL, nullptr, 1.f, 0);
            const float* giP = gi;
            u16* soP = seqOut;
            int s0v = seg * 128;
            int sbv = (l * 4 + seg) * 128;
            void* args[] = { (void*)&giP, (void*)&WhL, (void*)&bhL, (void*)&soP,
                             (void*)&hg, (void*)&cnt, (void*)&s0v, (void*)&sbv };
            hipLaunchCooperativeKernel((void*)gru_coop, dim3(256), dim3(256),
                                       args, 0, stream);
        }
    }

    final_kernel<<<8192, 256, 0, stream>>>(h2bf, Wf, bfin, out);
}